// Round 1
// baseline (95.626 us; speedup 1.0000x reference)
//
#include <hip/hip_runtime.h>

#define NB   2
#define NCO  8
#define NCI  8
#define ND   8
#define NGH  16
#define NGW  16
#define NH   512
#define NW   512
#define NP   5   // ceil(35*35 / 256) = 5 pixels per thread max

// One block per (b, cell_y, cell_x). All pixels in a block share (y0,x0) = (cy,cx).
__global__ __launch_bounds__(256, 2) void bslice_kernel(
    const float* __restrict__ grid,
    const float* __restrict__ guide,
    const float* __restrict__ inp,
    float* __restrict__ out)
{
    const int tid = threadIdx.x;
    const int cx  = blockIdx.x;   // 0..14
    const int cy  = blockIdx.y;   // 0..14
    const int b   = blockIdx.z;

    // pixel range covered by this cell: x with min(floor(x*15/511),14) == cx
    const int xs = (cx * (NW - 1) + (NGW - 2)) / (NGW - 1);            // ceil(cx*511/15)
    const int xe = (cx == NGW - 2) ? NW : (((cx + 1) * (NW - 1) + (NGW - 2)) / (NGW - 1));
    const int ys = (cy * (NH - 1) + (NGH - 2)) / (NGH - 1);
    const int ye = (cy == NGH - 2) ? NH : (((cy + 1) * (NH - 1) + (NGH - 2)) / (NGH - 1));

    // Stage the cell's grid values: [co][dy][dx][k][z], k=1 (bias) pre-scaled by 1/8.
    __shared__ float sg[NCO * 2 * 2 * 2 * ND];   // 512 floats
    for (int i = tid; i < NCO * 64; i += 256) {
        int z  = i & 7;
        int k  = (i >> 3) & 1;
        int dx = (i >> 4) & 1;
        int dy = (i >> 5) & 1;
        int co = i >> 6;
        float v = grid[((((size_t)(b * NCO + co) * 2 + k) * ND + z) * NGH + (cy + dy)) * NGW + (cx + dx)];
        sg[i] = k ? v * 0.125f : v;
    }
    __syncthreads();

    const unsigned wcell = (unsigned)(xe - xs);
    const int npix = (int)wcell * (ye - ys);

    float S0[NP][8], S1[NP][8];
    float wgt[NP][4];
    int   poff[NP];
    bool  val[NP];

    const float step = (float)(NGH - 1) / (float)(NH - 1);   // 15/511 (square image)
    const size_t inbase = (size_t)b * NCI * NH * NW;

    #pragma unroll
    for (int p = 0; p < NP; ++p) {
        int i = tid + p * 256;
        val[p] = (i < npix);
        unsigned ii = val[p] ? (unsigned)i : 0u;
        unsigned q  = ii / wcell;
        int py = ys + (int)q;
        int px = xs + (int)(ii - q * wcell);

        float wy = (float)py * step - (float)cy;   // in (0,1]
        float wx = (float)px * step - (float)cx;
        wgt[p][0] = (1.f - wy) * (1.f - wx);
        wgt[p][1] = (1.f - wy) * wx;
        wgt[p][2] = wy * (1.f - wx);
        wgt[p][3] = wy * wx;

        int off = py * NW + px;
        poff[p] = off;

        #pragma unroll
        for (int z = 0; z < 8; ++z) { S0[p][z] = 0.f; S1[p][z] = 0.f; }

        const float* gp = guide + inbase + off;
        const float* vp = inp   + inbase + off;
        #pragma unroll
        for (int ci = 0; ci < NCI; ++ci) {
            float g = gp[(size_t)ci * NH * NW];
            float v = vp[(size_t)ci * NH * NW];
            float zp = fminf(fmaxf(g * 7.0f, 0.0f), 7.0f);
            #pragma unroll
            for (int z = 0; z < 8; ++z) {
                float a = fmaxf(0.0f, 1.0f - fabsf(zp - (float)z));
                S0[p][z] = fmaf(a, v, S0[p][z]);
                S1[p][z] += a;
            }
        }
    }

    const size_t obase = (size_t)b * NCO * NH * NW;

    #pragma unroll 1   // keep code size down; inner loops fully unrolled
    for (int co = 0; co < NCO; ++co) {
        // 64-float slice for this co, held in registers, reused over NP pixels.
        float4 s[16];
        #pragma unroll
        for (int j = 0; j < 16; ++j)
            s[j] = *(const float4*)&sg[co * 64 + j * 4];

        #pragma unroll
        for (int p = 0; p < NP; ++p) {
            float acc = 0.f;
            #pragma unroll
            for (int c = 0; c < 4; ++c) {
                float4 g0l = s[c * 4 + 0];   // weight z0..3
                float4 g0h = s[c * 4 + 1];   // weight z4..7
                float4 g1l = s[c * 4 + 2];   // bias/8 z0..3
                float4 g1h = s[c * 4 + 3];   // bias/8 z4..7
                float t;
                t = S0[p][0] * g0l.x;
                t = fmaf(S0[p][1], g0l.y, t);
                t = fmaf(S0[p][2], g0l.z, t);
                t = fmaf(S0[p][3], g0l.w, t);
                t = fmaf(S0[p][4], g0h.x, t);
                t = fmaf(S0[p][5], g0h.y, t);
                t = fmaf(S0[p][6], g0h.z, t);
                t = fmaf(S0[p][7], g0h.w, t);
                t = fmaf(S1[p][0], g1l.x, t);
                t = fmaf(S1[p][1], g1l.y, t);
                t = fmaf(S1[p][2], g1l.z, t);
                t = fmaf(S1[p][3], g1l.w, t);
                t = fmaf(S1[p][4], g1h.x, t);
                t = fmaf(S1[p][5], g1h.y, t);
                t = fmaf(S1[p][6], g1h.z, t);
                t = fmaf(S1[p][7], g1h.w, t);
                acc = fmaf(wgt[p][c], t, acc);
            }
            if (val[p])
                out[obase + (size_t)co * NH * NW + poff[p]] = acc;
        }
    }
}

extern "C" void kernel_launch(void* const* d_in, const int* in_sizes, int n_in,
                              void* d_out, int out_size, void* d_ws, size_t ws_size,
                              hipStream_t stream) {
    const float* grid  = (const float*)d_in[0];
    const float* guide = (const float*)d_in[1];
    const float* inp   = (const float*)d_in[2];
    float* out = (float*)d_out;

    dim3 g(NGW - 1, NGH - 1, NB);   // (15, 15, 2) cells
    bslice_kernel<<<g, 256, 0, stream>>>(grid, guide, inp, out);
}